// Round 5
// baseline (3366.039 us; speedup 1.0000x reference)
//
#include <hip/hip_runtime.h>
#include <math.h>

#define N_PTS 262144
#define D 128
#define K_CL 120
#define XST 136   // xs stride (u16): 272 B rows; 8-elem blocks XOR-swizzled by (row>>2)&7
#define CST 72    // cs chunk stride (u16) for 64-dim chunks (m92-verified pattern)
#define LST 72    // CE kernel LDS stride

typedef short bf16x8 __attribute__((ext_vector_type(8)));
typedef float floatx4 __attribute__((ext_vector_type(4)));

__device__ __forceinline__ unsigned f2bf(float f) {
    unsigned u = __float_as_uint(f);
    u += 0x7fffu + ((u >> 16) & 1u);   // RNE
    return u >> 16;
}

// ---------------------------------------------------------------------------
// init: cb = bf16(x[:120]), csq = rowwise sumsq (fp32).  grid 240 x 128
__global__ __launch_bounds__(128) void init_kernel(
    const float* __restrict__ f1, const float* __restrict__ f2,
    unsigned short* __restrict__ cb1, unsigned short* __restrict__ cb2,
    float* __restrict__ csq1, float* __restrict__ csq2)
{
    int b = blockIdx.x;
    const float* src = (b < K_CL) ? f1 : f2;
    unsigned short* cb = (b < K_CL) ? cb1 : cb2;
    float* dsq          = (b < K_CL) ? csq1 : csq2;
    int j = (b < K_CL) ? b : (b - K_CL);
    int d = threadIdx.x;
    float v = src[(long)j * D + d];
    cb[j * D + d] = (unsigned short)f2bf(v);
    float sq = v * v;
#pragma unroll
    for (int w = 1; w < 64; w <<= 1) sq += __shfl_xor(sq, w, 64);
    __shared__ float tmp[2];
    if ((d & 63) == 0) tmp[d >> 6] = sq;
    __syncthreads();
    if (d == 0) dsq[j] = tmp[0] + tmp[1];
}

// ---------------------------------------------------------------------------
// fused assign+accumulate.  grid 512 x 256, 4 tiles of 128 points per block.
// Score: S_T[cluster][point] = C.X^T (MFMA, all-b128 LDS).  Argmin -> cl.
// Accum: sums += onehot.X (MFMA); B-frags via contiguous b128 reads + in-lane
//   8x8 u16 transpose (v_perm), column n of MFMA #nt mapped to dim c16*8+nt.
// MODE: 0 = fp32 input; 1 = fp32 input + write bf16 copy; 2 = bf16 input.
template<int MODE>
__global__ __launch_bounds__(256)
__attribute__((amdgpu_waves_per_eu(2, 2)))
void fused_kernel(
    const float* __restrict__ xf, unsigned short* __restrict__ xb,
    const unsigned short* __restrict__ cb, const float* __restrict__ csq,
    int* __restrict__ cl, float* __restrict__ sums, float* __restrict__ counts)
{
    __shared__ unsigned short xs[128 * XST];
    __shared__ unsigned short cs[128 * CST];
    __shared__ float scs[128];
    __shared__ int   cl_s[128];
    __shared__ float s_c[128];

    int tid = threadIdx.x, lane = tid & 63, w = tid >> 6;
    int q = lane >> 4, c16 = lane & 15;

    if (tid < 128) { scs[tid] = (tid < K_CL) ? csq[tid] : 3.0e38f; s_c[tid] = 0.f; }

    floatx4 acc[2][8];                  // accum: clusters w*32+{0,16}+.., dims via c16*8+nt
#pragma unroll
    for (int mt = 0; mt < 2; mt++)
#pragma unroll
        for (int nt = 0; nt < 8; nt++) acc[mt][nt] = (floatx4){0.f, 0.f, 0.f, 0.f};

    for (int t = 0; t < 4; t++) {
        long base = ((long)blockIdx.x * 4 + t) * 128;
        __syncthreads();                // prev tile xs/cl_s fully consumed
        // ---- stage xs: 128 pts x 128 dims bf16; block-swizzle by (m>>2)&7
#pragma unroll
        for (int l = 0; l < 8; l++) {
            int idx = tid + 256 * l;    // 0..2047
            int m = idx >> 4, k8 = idx & 15;
            int soff = m * XST + ((k8 ^ ((m >> 2) & 7)) << 3);
            if (MODE == 2) {
                int4 v = *(const int4*)(xb + (long)(base + m) * D + k8 * 8);
                *(int4*)(&xs[soff]) = v;
            } else {
                const float4* p = (const float4*)(xf + (long)(base + m) * D + k8 * 8);
                float4 v0 = p[0], v1 = p[1];
                int4 wv;
                wv.x = (int)(f2bf(v0.x) | (f2bf(v0.y) << 16));
                wv.y = (int)(f2bf(v0.z) | (f2bf(v0.w) << 16));
                wv.z = (int)(f2bf(v1.x) | (f2bf(v1.y) << 16));
                wv.w = (int)(f2bf(v1.z) | (f2bf(v1.w) << 16));
                *(int4*)(&xs[soff]) = wv;
                if (MODE == 1)
                    *(int4*)(xb + (long)(base + m) * D + k8 * 8) = wv;
            }
        }
        // ---- score phase
        floatx4 sacc[8][2];
#pragma unroll
        for (int mt = 0; mt < 8; mt++)
#pragma unroll
            for (int nt = 0; nt < 2; nt++) sacc[mt][nt] = (floatx4){0.f, 0.f, 0.f, 0.f};

#pragma unroll
        for (int half = 0; half < 2; half++) {
            // stage cs chunk: 128 clusters x 64 dims (pad >=K_CL with 0)
#pragma unroll
            for (int l = 0; l < 4; l++) {
                int idx = tid + 256 * l;     // 0..1023
                int n = idx >> 3, k8 = idx & 7;
                int4 v = make_int4(0, 0, 0, 0);
                if (n < K_CL) v = *(const int4*)(cb + n * D + half * 64 + k8 * 8);
                *(int4*)(&cs[n * CST + k8 * 8]) = v;
            }
            __syncthreads();                 // xs + cs chunk ready
#pragma unroll
            for (int s = 0; s < 2; s++) {
                bf16x8 b[2];
#pragma unroll
                for (int nt = 0; nt < 2; nt++) {
                    int r = w * 32 + nt * 16 + c16;
                    int kb = half * 8 + s * 4 + q;
                    b[nt] = *(const bf16x8*)(&xs[r * XST + ((kb ^ ((r >> 2) & 7)) << 3)]);
                }
#pragma unroll
                for (int mt = 0; mt < 8; mt++) {
                    bf16x8 a = *(const bf16x8*)(&cs[(mt * 16 + c16) * CST + s * 32 + q * 8]);
#pragma unroll
                    for (int nt = 0; nt < 2; nt++)
                        sacc[mt][nt] = __builtin_amdgcn_mfma_f32_16x16x32_bf16(
                            a, b[nt], sacc[mt][nt], 0, 0, 0);
                }
            }
            __syncthreads();                 // chunk reads done before restage
        }
        // ---- argmin epilogue: score = csq[c] - 2*dot; C/D col=point, row=cluster
#pragma unroll
        for (int nt = 0; nt < 2; nt++) {
            float best = 3.9e38f; int bi = 0;
#pragma unroll
            for (int mt = 0; mt < 8; mt++) {
                float4 sv = *(const float4*)(&scs[mt * 16 + q * 4]);
                int nb = mt * 16 + q * 4;
                float s0 = sv.x - 2.f * sacc[mt][nt][0];
                if (s0 < best) { best = s0; bi = nb + 0; }
                float s1 = sv.y - 2.f * sacc[mt][nt][1];
                if (s1 < best) { best = s1; bi = nb + 1; }
                float s2 = sv.z - 2.f * sacc[mt][nt][2];
                if (s2 < best) { best = s2; bi = nb + 2; }
                float s3 = sv.w - 2.f * sacc[mt][nt][3];
                if (s3 < best) { best = s3; bi = nb + 3; }
            }
#pragma unroll
            for (int wm = 16; wm <= 32; wm <<= 1) {
                float ov = __shfl_xor(best, wm, 64);
                int   oi = __shfl_xor(bi,   wm, 64);
                if (ov < best || (ov == best && oi < bi)) { best = ov; bi = oi; }
            }
            if (q == 0) {
                int p = w * 32 + nt * 16 + c16;
                cl_s[p] = bi;
                cl[base + p] = bi;
                atomicAdd(&s_c[bi], 1.0f);
            }
        }
        __syncthreads();                     // cl_s ready for accum
        // ---- accum: A = onehot (regs); B via b128 reads + in-lane transpose
        int mcl0 = w * 32 + c16, mcl1 = mcl0 + 16;
#pragma unroll
        for (int s = 0; s < 4; s++) {
            int kbase = s * 32 + q * 8;
            int4 cA = *(const int4*)(&cl_s[kbase]);
            int4 cB = *(const int4*)(&cl_s[kbase + 4]);
            int cls[8] = {cA.x, cA.y, cA.z, cA.w, cB.x, cB.y, cB.z, cB.w};
            bf16x8 a0, a1;
#pragma unroll
            for (int j = 0; j < 8; j++) {
                a0[j] = (cls[j] == mcl0) ? (short)0x3F80 : (short)0;
                a1[j] = (cls[j] == mcl1) ? (short)0x3F80 : (short)0;
            }
            // lane reads its 8 contiguous dims (block #c16) for 8 points
            unsigned r32[8][4];
#pragma unroll
            for (int j = 0; j < 8; j++) {
                int row = kbase + j;
                *(int4*)(&r32[j][0]) =
                    *(const int4*)(&xs[row * XST + ((c16 ^ ((row >> 2) & 7)) << 3)]);
            }
#pragma unroll
            for (int nt = 0; nt < 8; nt++) {
                const int k = nt >> 1;
                const unsigned sel = (nt & 1) ? 0x07060302u : 0x05040100u;
                unsigned bt[4];
                bt[0] = __builtin_amdgcn_perm(r32[1][k], r32[0][k], sel);
                bt[1] = __builtin_amdgcn_perm(r32[3][k], r32[2][k], sel);
                bt[2] = __builtin_amdgcn_perm(r32[5][k], r32[4][k], sel);
                bt[3] = __builtin_amdgcn_perm(r32[7][k], r32[6][k], sel);
                bf16x8 bv = *(bf16x8*)bt;
                acc[0][nt] = __builtin_amdgcn_mfma_f32_16x16x32_bf16(a0, bv, acc[0][nt], 0, 0, 0);
                acc[1][nt] = __builtin_amdgcn_mfma_f32_16x16x32_bf16(a1, bv, acc[1][nt], 0, 0, 0);
            }
        }
    }
    __syncthreads();                         // s_c complete
    // ---- flush: row=cluster (q*4+reg), MFMA #nt column c16 -> dim c16*8+nt
#pragma unroll
    for (int mt = 0; mt < 2; mt++)
#pragma unroll
        for (int nt = 0; nt < 8; nt++)
#pragma unroll
            for (int reg = 0; reg < 4; reg++) {
                int cluster = w * 32 + mt * 16 + q * 4 + reg;
                int dim = c16 * 8 + nt;
                unsafeAtomicAdd(&sums[cluster * D + dim], acc[mt][nt][reg]);
            }
    if (tid < 128) unsafeAtomicAdd(&counts[tid], s_c[tid]);
}

// ---------------------------------------------------------------------------
// CE: loss_i = logsumexp(x_i.C^T/T) - x_i.c[label]/T; block partial -> part.
template<bool BF>
__global__ __launch_bounds__(256) void ce_kernel(
    const float* __restrict__ xf, const unsigned short* __restrict__ xb,
    const unsigned short* __restrict__ cb,
    const int* __restrict__ cl, float* __restrict__ part)
{
    __shared__ unsigned short xsm[128 * LST];
    __shared__ unsigned short csm[128 * LST];
    __shared__ float red[4];

    int tid  = threadIdx.x;
    int lane = tid & 63, wave = tid >> 6;
    int q = lane >> 4, c16 = lane & 15;
    long base = (long)blockIdx.x * 128;

    floatx4 acc[2][8];
#pragma unroll
    for (int ri = 0; ri < 2; ri++)
#pragma unroll
        for (int cj = 0; cj < 8; cj++) acc[ri][cj] = (floatx4){0.f, 0.f, 0.f, 0.f};

    for (int kc = 0; kc < D; kc += 64) {
        __syncthreads();
#pragma unroll
        for (int l = 0; l < 8; l++) {
            int idx = tid + 256 * l;
            int m = idx >> 4, k4 = idx & 15;
            uint2 wv;
            if (BF) {
                wv = *(const uint2*)(xb + (base + m) * D + kc + k4 * 4);
            } else {
                float4 v = *(const float4*)(xf + (base + m) * D + kc + k4 * 4);
                wv.x = f2bf(v.x) | (f2bf(v.y) << 16);
                wv.y = f2bf(v.z) | (f2bf(v.w) << 16);
            }
            *(uint2*)(&xsm[m * LST + k4 * 4]) = wv;
        }
#pragma unroll
        for (int l = 0; l < 8; l++) {
            int idx = tid + 256 * l;
            int n = idx >> 4, k4 = idx & 15;
            uint2 wv = make_uint2(0u, 0u);
            if (n < K_CL) wv = *(const uint2*)(cb + (long)n * D + kc + k4 * 4);
            *(uint2*)(&csm[n * LST + k4 * 4]) = wv;
        }
        __syncthreads();
#pragma unroll
        for (int s = 0; s < 2; s++) {
            int kk = s * 32 + q * 8;
            bf16x8 a[2], b[8];
#pragma unroll
            for (int ri = 0; ri < 2; ri++)
                a[ri] = *(const bf16x8*)(&xsm[(wave * 32 + ri * 16 + c16) * LST + kk]);
#pragma unroll
            for (int cj = 0; cj < 8; cj++)
                b[cj] = *(const bf16x8*)(&csm[(cj * 16 + c16) * LST + kk]);
#pragma unroll
            for (int ri = 0; ri < 2; ri++)
#pragma unroll
                for (int cj = 0; cj < 8; cj++)
                    acc[ri][cj] = __builtin_amdgcn_mfma_f32_16x16x32_bf16(
                        a[ri], b[cj], acc[ri][cj], 0, 0, 0);
        }
    }

    const float invT = 2.5f;
    float th_loss = 0.f;
#pragma unroll
    for (int ri = 0; ri < 2; ri++) {
#pragma unroll
        for (int reg = 0; reg < 4; reg++) {
            long m = base + wave * 32 + ri * 16 + q * 4 + reg;
            int lbl = cl[m];
            float L[8];
            float lmax = -3.0e38f;
#pragma unroll
            for (int cj = 0; cj < 8; cj++) {
                int n = cj * 16 + c16;
                L[cj] = (n < K_CL) ? invT * acc[ri][cj][reg] : -3.0e38f;
                lmax = fmaxf(lmax, L[cj]);
            }
#pragma unroll
            for (int w = 1; w < 16; w <<= 1) lmax = fmaxf(lmax, __shfl_xor(lmax, w, 64));
            float se = 0.f, lsel = 0.f;
#pragma unroll
            for (int cj = 0; cj < 8; cj++) {
                int n = cj * 16 + c16;
                if (n < K_CL) {
                    se += __expf(L[cj] - lmax);
                    if (n == lbl) lsel = L[cj];
                }
            }
#pragma unroll
            for (int w = 1; w < 16; w <<= 1) {
                se   += __shfl_xor(se,   w, 64);
                lsel += __shfl_xor(lsel, w, 64);
            }
            if (c16 == 0) th_loss += (lmax + __logf(se)) - lsel;
        }
    }
#pragma unroll
    for (int w = 1; w < 64; w <<= 1) th_loss += __shfl_xor(th_loss, w, 64);
    if (lane == 0) red[wave] = th_loss;
    __syncthreads();
    if (tid == 0) part[blockIdx.x] = red[0] + red[1] + red[2] + red[3];
}

// ---------------------------------------------------------------------------
// update: c = sums/max(cnt,1-if-0); bf16 copy + csq; re-zero sums/counts.
__global__ __launch_bounds__(128) void update_kernel(
    unsigned short* __restrict__ cb, float* __restrict__ csq,
    float* __restrict__ sums, float* __restrict__ counts)
{
    int j = blockIdx.x, d = threadIdx.x;
    float cnt = counts[j];
    float div = (cnt == 0.f) ? 1.f : cnt;
    float v = sums[j * D + d] / div;
    cb[j * D + d] = (unsigned short)f2bf(v);
    sums[j * D + d] = 0.f;
    float sq = v * v;
#pragma unroll
    for (int w = 1; w < 64; w <<= 1) sq += __shfl_xor(sq, w, 64);
    __shared__ float tmp[2];
    if ((d & 63) == 0) tmp[d >> 6] = sq;
    __syncthreads();
    if (d == 0) { csq[j] = tmp[0] + tmp[1]; counts[j] = 0.f; }
}

// ---------------------------------------------------------------------------
__global__ __launch_bounds__(256) void final_kernel(
    const float* __restrict__ part, float* __restrict__ out)
{
    int tid = threadIdx.x;
    float s = 0.f;
#pragma unroll
    for (int k = 0; k < 16; k++) s += part[tid + 256 * k];
#pragma unroll
    for (int w = 1; w < 64; w <<= 1) s += __shfl_xor(s, w, 64);
    __shared__ float tmp[4];
    if ((tid & 63) == 0) tmp[tid >> 6] = s;
    __syncthreads();
    if (tid == 0)
        out[0] = (tmp[0] + tmp[1] + tmp[2] + tmp[3]) * (0.5f / (float)N_PTS);
}

// ---------------------------------------------------------------------------
extern "C" void kernel_launch(void* const* d_in, const int* in_sizes, int n_in,
                              void* d_out, int out_size, void* d_ws, size_t ws_size,
                              hipStream_t stream)
{
    const float* f1 = (const float*)d_in[0];
    const float* f2 = (const float*)d_in[1];
    float* out = (float*)d_out;

    char* ws = (char*)d_ws;
    char* ws0 = ws;
    unsigned short* cb1 = (unsigned short*)ws; ws += K_CL * D * sizeof(short);
    unsigned short* cb2 = (unsigned short*)ws; ws += K_CL * D * sizeof(short);
    float* csq1 = (float*)ws; ws += 128 * sizeof(float);
    float* csq2 = (float*)ws; ws += 128 * sizeof(float);
    float* sums = (float*)ws; ws += 128 * D * sizeof(float);
    float* cnts = (float*)ws; ws += 128 * sizeof(float);      // contiguous w/ sums
    float* part = (float*)ws; ws += 4096 * sizeof(float);
    int* cl1    = (int*)ws;   ws += (size_t)N_PTS * sizeof(int);
    int* cl2    = (int*)ws;   ws += (size_t)N_PTS * sizeof(int);
    unsigned short* xb1 = (unsigned short*)ws; ws += (size_t)N_PTS * D * sizeof(short);
    unsigned short* xb2 = (unsigned short*)ws; ws += (size_t)N_PTS * D * sizeof(short);
    bool usebf = ((size_t)(ws - ws0) <= ws_size);

    hipMemsetAsync(sums, 0, (128 * D + 128) * sizeof(float), stream);
    init_kernel<<<240, 128, 0, stream>>>(f1, f2, cb1, cb2, csq1, csq2);

    if (usebf) {
        // iter 0: stage from fp32, emit bf16 copies as a side effect
        fused_kernel<1><<<512, 256, 0, stream>>>(f1, xb1, cb1, csq1, cl1, sums, cnts);
        update_kernel<<<K_CL, 128, 0, stream>>>(cb1, csq1, sums, cnts);
        fused_kernel<1><<<512, 256, 0, stream>>>(f2, xb2, cb2, csq2, cl2, sums, cnts);
        update_kernel<<<K_CL, 128, 0, stream>>>(cb2, csq2, sums, cnts);
        for (int it = 1; it < 5; ++it) {
            fused_kernel<2><<<512, 256, 0, stream>>>(nullptr, xb1, cb1, csq1, cl1, sums, cnts);
            update_kernel<<<K_CL, 128, 0, stream>>>(cb1, csq1, sums, cnts);
            fused_kernel<2><<<512, 256, 0, stream>>>(nullptr, xb2, cb2, csq2, cl2, sums, cnts);
            update_kernel<<<K_CL, 128, 0, stream>>>(cb2, csq2, sums, cnts);
        }
        ce_kernel<true><<<N_PTS / 128, 256, 0, stream>>>(f1, xb1, cb2, cl2, part);
        ce_kernel<true><<<N_PTS / 128, 256, 0, stream>>>(f2, xb2, cb1, cl1, part + 2048);
    } else {
        for (int it = 0; it < 5; ++it) {
            fused_kernel<0><<<512, 256, 0, stream>>>(f1, nullptr, cb1, csq1, cl1, sums, cnts);
            update_kernel<<<K_CL, 128, 0, stream>>>(cb1, csq1, sums, cnts);
            fused_kernel<0><<<512, 256, 0, stream>>>(f2, nullptr, cb2, csq2, cl2, sums, cnts);
            update_kernel<<<K_CL, 128, 0, stream>>>(cb2, csq2, sums, cnts);
        }
        ce_kernel<false><<<N_PTS / 128, 256, 0, stream>>>(f1, nullptr, cb2, cl2, part);
        ce_kernel<false><<<N_PTS / 128, 256, 0, stream>>>(f2, nullptr, cb1, cl1, part + 2048);
    }
    final_kernel<<<1, 256, 0, stream>>>(part, out);
}